// Round 1
// baseline (531.098 us; speedup 1.0000x reference)
//
#include <hip/hip_runtime.h>
#include <stdint.h>

typedef __bf16 bf16_t;
typedef __bf16 bf16x8 __attribute__((ext_vector_type(8)));
typedef __bf16 bf16x4 __attribute__((ext_vector_type(4)));
typedef float  f32x16 __attribute__((ext_vector_type(16)));
typedef float  f32x4  __attribute__((ext_vector_type(4)));

#define MFMA_B16(a, b, c) __builtin_amdgcn_mfma_f32_32x32x16_bf16((a), (b), (c), 0, 0, 0)

static constexpr int kG = 4, kD = 4, kH = 512;
static constexpr int kW0T = 4 * 256 * 128;            // 131072 elements
static constexpr int kWgT = 3 * 4 * 4 * 128 * 128;    // 786432 elements

// sigma: within a 32-wide n-tile, position n=[gi1 gi0 h r1 r0] -> logical unit
// u=[gi0 h gi1 r1 r0]. With weight columns stored permuted by sigma, the MFMA
// C/D quads of one step are directly the B-operand fragments of the next step.
__device__ __host__ inline int sigma_tile(int n) {
  int gi = n >> 3, h = (n >> 2) & 1, r = n & 3;
  return 16 * (gi & 1) + 8 * h + 4 * (gi >> 1) + r;
}

// ---------------------------------------------------------------------------
// Prep: f32 weights -> bf16 frag-linear, columns permuted by sigma.
//   w0t: [g][f = kt*4+nt][ln][j]  kt 0..15 (K=256 DIN, identity on k)
//   wgt: [g][m = l*4+d][f = kt*4+nt][ln][j]  kt 0..7 (K=128, u-space identity)
// ---------------------------------------------------------------------------
__global__ __launch_bounds__(256) void prep_weights(
    const float* __restrict__ W0, const float* __restrict__ Wg,
    bf16_t* __restrict__ w0t, bf16_t* __restrict__ wgt)
{
  int e = blockIdx.x * 256 + threadIdx.x;
  if (e < kW0T) {
    int g  = e >> 15;
    int r  = e & 32767;
    int f  = r >> 9;
    int ln = (r >> 3) & 63;
    int j  = r & 7;
    int kt = f >> 2, nt = f & 3;
    int col = nt * 32 + sigma_tile(ln & 31);
    int k   = kt * 16 + ((ln >> 5) << 3) + j;
    w0t[e] = (bf16_t)W0[k * kH + g * 128 + col];
  } else if (e < kW0T + kWgT) {
    int e2 = e - kW0T;
    int g  = e2 / (12 * 16384);
    int r2 = e2 - g * (12 * 16384);
    int m  = r2 >> 14;           // l*4 + d
    int r  = r2 & 16383;
    int f  = r >> 9;
    int ln = (r >> 3) & 63;
    int j  = r & 7;
    int kt = f >> 2, nt = f & 3;
    int col = nt * 32 + sigma_tile(ln & 31);
    int k   = kt * 16 + ((ln >> 5) << 3) + j;
    int l   = m >> 2, d = m & 3;
    wgt[e2] = (bf16_t)Wg[((((l * kG + g) * kD + d) * 128) + k) * 128 + col];
  }
}

// ---------------------------------------------------------------------------
// Fused network, register-resident h. Block = 128 rows x one group; 4 waves,
// wave w owns rows r0+32w..+31 (lane row = base + (ln&31)) and full n=0..127.
// acc[t] (t = n-tile) f32x16; C quad (t,gi) holds logical unit
// u = 32t+16(gi&1)+8l5+4(gi>>1)+r, so frag(kt) = [quad(kt>>1, kt&1),
// quad(kt>>1, 2+(kt&1))] -- pure register aliasing (keepA/keepB).
//
// Weights: NO LDS staging, NO per-step barriers. Per-step 32KB tile is hot in
// L1/L2 (shared by 512 same-g blocks); each wave reads its A-fragments as
// coalesced 1KB global loads with a 1-kt-deep a0/a1 register ping-pong
// (compiler emits counted vmcnt, not a drain). Next step's kt=0 frags are
// issued before the epilogue so epilogue VALU hides their latency.
// Final store via XOR-swizzled LDS f32 transpose -> full-line coalesced writes.
// ---------------------------------------------------------------------------
__global__ __launch_bounds__(256, 2) void resnext_fused(
    const float* __restrict__ x, const float* __restrict__ b0,
    const float* __restrict__ bg, const bf16_t* __restrict__ w0t,
    const bf16_t* __restrict__ wgt, float* __restrict__ out)
{
  __shared__ float sT[128 * 128];     // 64 KB: final-store transpose tile
  __shared__ float sBias[13 * 128];   // slot 0 = b0, slots 1..12 = bg steps

  const int tid = threadIdx.x;
  const int ln  = tid & 63;
  const int wv  = tid >> 6;
  const int l31 = ln & 31;
  const int l5  = ln >> 5;

  const int g  = blockIdx.x >> 9;          // g-major: x streams once per g
  const int r0 = (blockIdx.x & 511) << 7;

  const bf16_t* wgt_g = wgt + g * (12 * 16384);

  // stage biases (b0 slice + 12 bg slices)
  for (int i = tid; i < 13 * 128; i += 256) {
    float v;
    if (i < 128) v = b0[g * 128 + i];
    else {
      int m = (i - 128) >> 7, u = (i - 128) & 127;
      int l = m >> 2, d = m & 3;
      v = bg[((l * kG + g) * kD + d) * 128 + u];
    }
    sBias[i] = v;
  }

  f32x16 acc[4];
  #pragma unroll
  for (int t = 0; t < 4; ++t)
    #pragma unroll
    for (int q = 0; q < 16; ++q) acc[t][q] = 0.f;

  // ---------- initial GEMM: K=256, A (W0t) from global/L2, B from x
  {
    const bf16_t* w0g = w0t + g * 32768;
    const float* xb = x + (size_t)(r0 + wv * 32 + l31) * 256 + l5 * 8;
    #pragma unroll
    for (int kt = 0; kt < 16; ++kt) {
      f32x4 xa = *(const f32x4*)(xb + kt * 16);
      f32x4 xc = *(const f32x4*)(xb + kt * 16 + 4);
      bf16x8 bfr;
      #pragma unroll
      for (int q = 0; q < 4; ++q) {
        bfr[q]     = (bf16_t)xa[q];
        bfr[q + 4] = (bf16_t)xc[q];
      }
      #pragma unroll
      for (int nt = 0; nt < 4; ++nt) {
        bf16x8 a = *(const bf16x8*)(w0g + (kt * 4 + nt) * 512 + ln * 8);
        acc[nt] = MFMA_B16(a, bfr, acc[nt]);
      }
    }
  }

  // prefetch chain step-0, kt=0 A-fragments (lands under barrier + epilogue)
  bf16x8 a0[4], a1[4];
  {
    const bf16_t* wl0 = wgt_g + ln * 8;
    #pragma unroll
    for (int nt = 0; nt < 4; ++nt) a0[nt] = *(const bf16x8*)(wl0 + nt * 512);
  }

  __syncthreads();   // sBias ready (the only pre-chain barrier)

  bf16x8 keepA[4], keepB[4], x0A[4], x0B[4], resA[4], resB[4];

  // ---------- initial epilogue: relu(x@W0 + b0) -> keep/x0/resid registers
  #pragma unroll
  for (int t = 0; t < 4; ++t) {
    #pragma unroll
    for (int gi = 0; gi < 4; ++gi) {
      f32x4 bv = *(const f32x4*)(sBias + 32 * t + 16 * (gi & 1) + 8 * l5 + 4 * (gi >> 1));
      #pragma unroll
      for (int r = 0; r < 4; ++r) {
        float v = acc[t][gi * 4 + r] + bv[r];
        v = fmaxf(v, 0.f);
        bf16_t o = (bf16_t)v;
        int half = (gi >> 1) * 4 + r;
        if (gi & 1) keepB[t][half] = o; else keepA[t][half] = o;
      }
    }
    x0A[t] = keepA[t]; x0B[t] = keepB[t];
    resA[t] = keepA[t]; resB[t] = keepB[t];
  }

  // ---------- chain steps m = 0..11 — barrier-free, weights direct from L2
  #pragma unroll 1
  for (int m = 0; m < 12; ++m) {
    const bf16_t* wl  = wgt_g + m * 16384 + ln * 8;
    const bf16_t* wlN = wl + 16384;

    #pragma unroll
    for (int t = 0; t < 4; ++t)
      #pragma unroll
      for (int q = 0; q < 16; ++q) acc[t][q] = 0.f;

    #pragma unroll
    for (int kt = 0; kt < 8; ++kt) {
      // 1-kt-deep prefetch into the inactive half of the a0/a1 ping-pong.
      if (kt < 7) {
        #pragma unroll
        for (int nt = 0; nt < 4; ++nt) {
          bf16x8 v = *(const bf16x8*)(wl + ((kt + 1) * 4 + nt) * 512);
          if (kt & 1) a0[nt] = v; else a1[nt] = v;
        }
      } else if (m < 11) {
        // next step's kt=0 frags: latency hidden under this step's epilogue
        #pragma unroll
        for (int nt = 0; nt < 4; ++nt)
          a0[nt] = *(const bf16x8*)(wlN + nt * 512);
      }
      bf16x8 bfr = (kt & 1) ? keepB[kt >> 1] : keepA[kt >> 1];
      #pragma unroll
      for (int nt = 0; nt < 4; ++nt)
        acc[nt] = MFMA_B16((kt & 1) ? a1[nt] : a0[nt], bfr, acc[nt]);
    }

    const bool layer_end = ((m & 3) == 3);
    const float* bptr = sBias + (m + 1) * 128;

    if (m < 11) {
      #pragma unroll
      for (int t = 0; t < 4; ++t) {
        #pragma unroll
        for (int gi = 0; gi < 4; ++gi) {
          f32x4 bv = *(const f32x4*)(bptr + 32 * t + 16 * (gi & 1) + 8 * l5 + 4 * (gi >> 1));
          #pragma unroll
          for (int r = 0; r < 4; ++r) {
            float v = acc[t][gi * 4 + r] + bv[r];
            v = fmaxf(v, 0.f);
            if (layer_end) {
              bf16x8 src = (gi & 1) ? resB[t] : resA[t];
              v += (float)src[(gi >> 1) * 4 + r];
              v = fmaxf(v, 0.f);
            }
            bf16_t o = (bf16_t)v;
            int half = (gi >> 1) * 4 + r;
            if (gi & 1) keepB[t][half] = o; else keepA[t][half] = o;
          }
        }
        if (layer_end) { resA[t] = keepA[t]; resB[t] = keepB[t]; }
      }
      // no barrier: next step's weights come straight from L1/L2
    } else {
      // final step: bias+relu, +resid relu, +x0 relu -> f32, via LDS transpose
      float fin[4][16];
      #pragma unroll
      for (int t = 0; t < 4; ++t) {
        #pragma unroll
        for (int gi = 0; gi < 4; ++gi) {
          f32x4 bv = *(const f32x4*)(bptr + 32 * t + 16 * (gi & 1) + 8 * l5 + 4 * (gi >> 1));
          #pragma unroll
          for (int r = 0; r < 4; ++r) {
            float v = acc[t][gi * 4 + r] + bv[r];
            v = fmaxf(v, 0.f);
            bf16x8 rs = (gi & 1) ? resB[t] : resA[t];
            v += (float)rs[(gi >> 1) * 4 + r];
            v = fmaxf(v, 0.f);
            bf16x8 xs = (gi & 1) ? x0B[t] : x0A[t];
            v += (float)xs[(gi >> 1) * 4 + r];
            v = fmaxf(v, 0.f);
            fin[t][gi * 4 + r] = v;
          }
        }
      }

      // write own tile (sT untouched until here; no pre-barrier needed)
      const int row = wv * 32 + l31;
      #pragma unroll
      for (int t = 0; t < 4; ++t) {
        #pragma unroll
        for (int gi = 0; gi < 4; ++gi) {
          int u = 32 * t + 16 * (gi & 1) + 8 * l5 + 4 * (gi >> 1);
          int col_s = u ^ ((l31 & 7) << 2);
          f32x4 v;
          #pragma unroll
          for (int r = 0; r < 4; ++r) v[r] = fin[t][gi * 4 + r];
          *(f32x4*)(sT + row * 128 + col_s) = v;
        }
      }
      __syncthreads();

      #pragma unroll
      for (int it = 0; it < 16; ++it) {
        int chunk = it * 256 + tid;
        int rw = chunk >> 5, c = chunk & 31;
        int col_s = (4 * c) ^ ((rw & 7) << 2);
        f32x4 v = *(const f32x4*)(sT + rw * 128 + col_s);
        *(f32x4*)(out + (size_t)(r0 + rw) * kH + g * 128 + 4 * c) = v;
      }
    }
  }
}

extern "C" void kernel_launch(void* const* d_in, const int* in_sizes, int n_in,
                              void* d_out, int out_size, void* d_ws, size_t ws_size,
                              hipStream_t stream) {
  const float* x  = (const float*)d_in[0];
  const float* W0 = (const float*)d_in[1];
  const float* b0 = (const float*)d_in[2];
  const float* Wg = (const float*)d_in[3];
  const float* bg = (const float*)d_in[4];
  float* outp = (float*)d_out;

  bf16_t* w0t = (bf16_t*)d_ws;
  bf16_t* wgt = w0t + kW0T;

  const int prep_total = kW0T + kWgT;
  prep_weights<<<(prep_total + 255) / 256, 256, 0, stream>>>(W0, Wg, w0t, wgt);

  resnext_fused<<<2048, 256, 0, stream>>>(x, b0, bg, w0t, wgt, outp);
}

// Round 2
// 473.152 us; speedup vs baseline: 1.1225x; 1.1225x over previous
//
#include <hip/hip_runtime.h>
#include <stdint.h>

typedef __bf16 bf16_t;
typedef __bf16 bf16x8 __attribute__((ext_vector_type(8)));
typedef __bf16 bf16x4 __attribute__((ext_vector_type(4)));
typedef float  f32x16 __attribute__((ext_vector_type(16)));
typedef float  f32x4  __attribute__((ext_vector_type(4)));

#define MFMA_B16(a, b, c) __builtin_amdgcn_mfma_f32_32x32x16_bf16((a), (b), (c), 0, 0, 0)

static constexpr int kG = 4, kD = 4, kH = 512;
static constexpr int kW0T = 4 * 256 * 128;            // 131072 elements
static constexpr int kWgT = 3 * 4 * 4 * 128 * 128;    // 786432 elements

// sigma: within a 32-wide n-tile, position n=[gi1 gi0 h r1 r0] -> logical unit
// u=[gi0 h gi1 r1 r0]. With weight columns stored permuted by sigma, the MFMA
// C/D quads of one step are directly the B-operand fragments of the next step.
__device__ __host__ inline int sigma_tile(int n) {
  int gi = n >> 3, h = (n >> 2) & 1, r = n & 3;
  return 16 * (gi & 1) + 8 * h + 4 * (gi >> 1) + r;
}

// ---------------------------------------------------------------------------
// Prep: f32 weights -> bf16 frag-linear, columns permuted by sigma.
//   w0t: [g][f = kt*4+nt][ln][j]  kt 0..15 (K=256 DIN, identity on k)
//   wgt: [g][m = l*4+d][f = kt*4+nt][ln][j]  kt 0..7 (K=128, u-space identity)
// ---------------------------------------------------------------------------
__global__ __launch_bounds__(256) void prep_weights(
    const float* __restrict__ W0, const float* __restrict__ Wg,
    bf16_t* __restrict__ w0t, bf16_t* __restrict__ wgt)
{
  int e = blockIdx.x * 256 + threadIdx.x;
  if (e < kW0T) {
    int g  = e >> 15;
    int r  = e & 32767;
    int f  = r >> 9;
    int ln = (r >> 3) & 63;
    int j  = r & 7;
    int kt = f >> 2, nt = f & 3;
    int col = nt * 32 + sigma_tile(ln & 31);
    int k   = kt * 16 + ((ln >> 5) << 3) + j;
    w0t[e] = (bf16_t)W0[k * kH + g * 128 + col];
  } else if (e < kW0T + kWgT) {
    int e2 = e - kW0T;
    int g  = e2 / (12 * 16384);
    int r2 = e2 - g * (12 * 16384);
    int m  = r2 >> 14;           // l*4 + d
    int r  = r2 & 16383;
    int f  = r >> 9;
    int ln = (r >> 3) & 63;
    int j  = r & 7;
    int kt = f >> 2, nt = f & 3;
    int col = nt * 32 + sigma_tile(ln & 31);
    int k   = kt * 16 + ((ln >> 5) << 3) + j;
    int l   = m >> 2, d = m & 3;
    wgt[e2] = (bf16_t)Wg[((((l * kG + g) * kD + d) * 128) + k) * 128 + col];
  }
}

// ---------------------------------------------------------------------------
// Fused network, register-resident h. Block = 128 rows x one group; 4 waves,
// wave w owns rows r0+32w..+31 (lane row = base + (ln&31)) and full n=0..127.
// acc[t] (t = n-tile) f32x16; C quad (t,gi) holds logical unit
// u = 32t+16(gi&1)+8l5+4(gi>>1)+r, so frag(kt) = [quad(kt>>1, kt&1),
// quad(kt>>1, 2+(kt&1))] -- pure register aliasing (keepA/keepB).
//
// Weights: 2x32KB LDS double buffer via global_load_lds(16B). Sync per step is
// counted-vmcnt + RAW s_barrier (no compiler vmcnt(0) drain): stage(m+1) stays
// in flight across the barrier; top-of-step waits only the previous step's 8
// loads (vmcnt(8)). End-of-step lgkmcnt(0)+barrier protects the buffer being
// overwritten next step.
//
// Block order: r-major (g fastest) + bijective chunked XCD swizzle so the 4
// same-row blocks (g=0..3) are co-resident on one XCD -> x fetched once from
// HBM instead of 4x.
// Final store via XOR-swizzled LDS f32 transpose -> full-line coalesced writes.
// ---------------------------------------------------------------------------
__global__ __launch_bounds__(256, 2) void resnext_fused(
    const float* __restrict__ x, const float* __restrict__ b0,
    const float* __restrict__ bg, const bf16_t* __restrict__ w0t,
    const bf16_t* __restrict__ wgt, float* __restrict__ out)
{
  __shared__ bf16_t sW[2][16384];     // 64 KB: weight dbuf; reused as f32 tile
  __shared__ float  sBias[13 * 128];  // slot 0 = b0, slots 1..12 = bg steps

  const int tid = threadIdx.x;
  const int ln  = tid & 63;
  const int wv  = tid >> 6;
  const int l31 = ln & 31;
  const int l5  = ln >> 5;

  // bijective chunked XCD swizzle: hw round-robins bid%8 across XCDs; give
  // each XCD 256 consecutive LOGICAL blocks. Logical order is r-major with
  // g fastest -> the 4 g-blocks of one row-tile co-reside on one XCD.
  const int bid     = blockIdx.x;
  const int logical = (bid & 7) * 256 + (bid >> 3);
  const int g  = logical & 3;
  const int r0 = (logical >> 2) << 7;

  const bf16_t* wgt_g = wgt + g * (12 * 16384);

  // stage biases (b0 slice + 12 bg slices)
  for (int i = tid; i < 13 * 128; i += 256) {
    float v;
    if (i < 128) v = b0[g * 128 + i];
    else {
      int m = (i - 128) >> 7, u = (i - 128) & 127;
      int l = m >> 2, d = m & 3;
      v = bg[((l * kG + g) * kD + d) * 128 + u];
    }
    sBias[i] = v;
  }

  // async stage of chain step m -> buf (8 frags/wave, 1KB each, lane*16B dest)
  auto stage = [&](int m, int buf) {
    #pragma unroll
    for (int i = 0; i < 8; ++i) {
      int frag = wv * 8 + i;
      __builtin_amdgcn_global_load_lds(
          (const __attribute__((address_space(1))) void*)(wgt_g + m * 16384 + frag * 512 + ln * 8),
          (__attribute__((address_space(3))) void*)(&sW[buf][frag * 512]),
          16, 0, 0);
    }
  };

  stage(0, 0);   // step-0 weights in flight under the initial GEMM

  f32x16 acc[4];
  #pragma unroll
  for (int t = 0; t < 4; ++t)
    #pragma unroll
    for (int q = 0; q < 16; ++q) acc[t][q] = 0.f;

  // ---------- initial GEMM: K=256, A (W0t) from global/L2, B from x
  {
    const bf16_t* w0g = w0t + g * 32768;
    const float* xb = x + (size_t)(r0 + wv * 32 + l31) * 256 + l5 * 8;
    #pragma unroll
    for (int kt = 0; kt < 16; ++kt) {
      f32x4 xa = *(const f32x4*)(xb + kt * 16);
      f32x4 xc = *(const f32x4*)(xb + kt * 16 + 4);
      bf16x8 bfr;
      #pragma unroll
      for (int q = 0; q < 4; ++q) {
        bfr[q]     = (bf16_t)xa[q];
        bfr[q + 4] = (bf16_t)xc[q];
      }
      #pragma unroll
      for (int nt = 0; nt < 4; ++nt) {
        bf16x8 a = *(const bf16x8*)(w0g + (kt * 4 + nt) * 512 + ln * 8);
        acc[nt] = MFMA_B16(a, bfr, acc[nt]);
      }
    }
  }
  __syncthreads();   // full drain ONCE: sBias + step-0 weights + x loads done

  bf16x8 keepA[4], keepB[4], x0A[4], x0B[4], resA[4], resB[4];

  // ---------- initial epilogue: relu(x@W0 + b0) -> keep/x0/resid registers
  #pragma unroll
  for (int t = 0; t < 4; ++t) {
    #pragma unroll
    for (int gi = 0; gi < 4; ++gi) {
      f32x4 bv = *(const f32x4*)(sBias + 32 * t + 16 * (gi & 1) + 8 * l5 + 4 * (gi >> 1));
      #pragma unroll
      for (int r = 0; r < 4; ++r) {
        float v = acc[t][gi * 4 + r] + bv[r];
        v = fmaxf(v, 0.f);
        bf16_t o = (bf16_t)v;
        int half = (gi >> 1) * 4 + r;
        if (gi & 1) keepB[t][half] = o; else keepA[t][half] = o;
      }
    }
    x0A[t] = keepA[t]; x0B[t] = keepB[t];
    resA[t] = keepA[t]; resB[t] = keepB[t];
  }

  // ---------- chain steps m = 0..11: counted vmcnt, raw barriers, no drains
  #pragma unroll 1
  for (int m = 0; m < 12; ++m) {
    if (m < 11) {
      stage(m + 1, (m + 1) & 1);   // prefetch stays in flight across barriers
      // wait only the PREVIOUS step's 8 loads (8 newer remain outstanding)
      asm volatile("s_waitcnt vmcnt(8)" ::: "memory");
    } else {
      asm volatile("s_waitcnt vmcnt(0)" ::: "memory");  // last step: drain 8
    }
    __builtin_amdgcn_s_barrier();   // all waves' step-m weights landed

    const bf16_t* wb = sW[m & 1];
    #pragma unroll
    for (int t = 0; t < 4; ++t)
      #pragma unroll
      for (int q = 0; q < 16; ++q) acc[t][q] = 0.f;

    #pragma unroll
    for (int kt = 0; kt < 8; ++kt) {
      bf16x8 bfr = (kt & 1) ? keepB[kt >> 1] : keepA[kt >> 1];
      #pragma unroll
      for (int nt = 0; nt < 4; ++nt) {
        bf16x8 a = *(const bf16x8*)(wb + (kt * 4 + nt) * 512 + ln * 8);
        acc[nt] = MFMA_B16(a, bfr, acc[nt]);
      }
    }

    const bool layer_end = ((m & 3) == 3);
    const float* bptr = sBias + (m + 1) * 128;

    if (m < 11) {
      #pragma unroll
      for (int t = 0; t < 4; ++t) {
        #pragma unroll
        for (int gi = 0; gi < 4; ++gi) {
          f32x4 bv = *(const f32x4*)(bptr + 32 * t + 16 * (gi & 1) + 8 * l5 + 4 * (gi >> 1));
          #pragma unroll
          for (int r = 0; r < 4; ++r) {
            float v = acc[t][gi * 4 + r] + bv[r];
            v = fmaxf(v, 0.f);
            if (layer_end) {
              bf16x8 src = (gi & 1) ? resB[t] : resA[t];
              v += (float)src[(gi >> 1) * 4 + r];
              v = fmaxf(v, 0.f);
            }
            bf16_t o = (bf16_t)v;
            int half = (gi >> 1) * 4 + r;
            if (gi & 1) keepB[t][half] = o; else keepA[t][half] = o;
          }
        }
        if (layer_end) { resA[t] = keepA[t]; resB[t] = keepB[t]; }
      }
      // my LDS reads of sW[m&1] complete, then barrier: next iteration's
      // stage(m+2) overwrites sW[m&1] only after every wave passed here.
      asm volatile("s_waitcnt lgkmcnt(0)" ::: "memory");
      __builtin_amdgcn_s_barrier();
    } else {
      // final step: bias+relu, +resid relu, +x0 relu -> f32, via LDS transpose
      float fin[4][16];
      #pragma unroll
      for (int t = 0; t < 4; ++t) {
        #pragma unroll
        for (int gi = 0; gi < 4; ++gi) {
          f32x4 bv = *(const f32x4*)(bptr + 32 * t + 16 * (gi & 1) + 8 * l5 + 4 * (gi >> 1));
          #pragma unroll
          for (int r = 0; r < 4; ++r) {
            float v = acc[t][gi * 4 + r] + bv[r];
            v = fmaxf(v, 0.f);
            bf16x8 rs = (gi & 1) ? resB[t] : resA[t];
            v += (float)rs[(gi >> 1) * 4 + r];
            v = fmaxf(v, 0.f);
            bf16x8 xs = (gi & 1) ? x0B[t] : x0A[t];
            v += (float)xs[(gi >> 1) * 4 + r];
            v = fmaxf(v, 0.f);
            fin[t][gi * 4 + r] = v;
          }
        }
      }
      __syncthreads();   // everyone done reading sW before tile overwrite

      float* sT = (float*)sW;   // 128 x 128 f32 tile, XOR-swizzled columns
      const int row = wv * 32 + l31;
      #pragma unroll
      for (int t = 0; t < 4; ++t) {
        #pragma unroll
        for (int gi = 0; gi < 4; ++gi) {
          int u = 32 * t + 16 * (gi & 1) + 8 * l5 + 4 * (gi >> 1);
          int col_s = u ^ ((l31 & 7) << 2);
          f32x4 v;
          #pragma unroll
          for (int r = 0; r < 4; ++r) v[r] = fin[t][gi * 4 + r];
          *(f32x4*)(sT + row * 128 + col_s) = v;
        }
      }
      __syncthreads();

      #pragma unroll
      for (int it = 0; it < 16; ++it) {
        int chunk = it * 256 + tid;
        int rw = chunk >> 5, c = chunk & 31;
        int col_s = (4 * c) ^ ((rw & 7) << 2);
        f32x4 v = *(const f32x4*)(sT + rw * 128 + col_s);
        *(f32x4*)(out + (size_t)(r0 + rw) * kH + g * 128 + 4 * c) = v;
      }
    }
  }
}

extern "C" void kernel_launch(void* const* d_in, const int* in_sizes, int n_in,
                              void* d_out, int out_size, void* d_ws, size_t ws_size,
                              hipStream_t stream) {
  const float* x  = (const float*)d_in[0];
  const float* W0 = (const float*)d_in[1];
  const float* b0 = (const float*)d_in[2];
  const float* Wg = (const float*)d_in[3];
  const float* bg = (const float*)d_in[4];
  float* outp = (float*)d_out;

  bf16_t* w0t = (bf16_t*)d_ws;
  bf16_t* wgt = w0t + kW0T;

  const int prep_total = kW0T + kWgT;
  prep_weights<<<(prep_total + 255) / 256, 256, 0, stream>>>(W0, Wg, w0t, wgt);

  resnext_fused<<<2048, 256, 0, stream>>>(x, b0, bg, w0t, wgt, outp);
}

// Round 3
// 404.755 us; speedup vs baseline: 1.3121x; 1.1690x over previous
//
#include <hip/hip_runtime.h>
#include <stdint.h>

typedef __bf16 bf16_t;
typedef __bf16 bf16x8 __attribute__((ext_vector_type(8)));
typedef float  f32x4  __attribute__((ext_vector_type(4)));

#define MFMA16(a, b, c) __builtin_amdgcn_mfma_f32_16x16x32_bf16((a), (b), (c), 0, 0, 0)

static constexpr int kG = 4, kD = 4, kH = 512;
static constexpr int kW0T = 4 * 256 * 128;            // 131072 elements
static constexpr int kWgT = 3 * 4 * 4 * 128 * 128;    // 786432 elements

// sigma16: physical acc position p (0..127) -> logical unit u, chosen so that
// lane-quarter c4 = l>>4 holds exactly logical cols {32*kt + 8*c4 + e}, i.e.
// the 16x16x32 C/D slots of one step ARE the B-operand fragments of the next:
//   p = 16*nt + 4*c4 + q  ->  u = q + 4*(nt&1) + 8*c4 + 32*(nt>>1)
// and keep[kt] = concat(acc[2kt][0:4], acc[2kt+1][0:4]) (pure register repack).
__device__ __host__ inline int sigma16(int p) {
  return (p & 3) + 4 * ((p >> 4) & 1) + 8 * ((p >> 2) & 3) + 32 * (p >> 5);
}

// ---------------------------------------------------------------------------
// Prep: f32 weights -> bf16 frag-linear for 16x16x32, columns sigma16-permuted.
//   w0t: [g][f = ktl*8+nt][ln][e]  ktl 0..7  (K=256 DIN, identity on k)
//   wgt: [g][m = l*4+d][f = ktl*8+nt][ln][e]  ktl 0..3 (K=128, u-space on k)
// A-frag layout (verified analog of 32x32x16): i = ln&15, k = 8*(ln>>4)+e.
// ---------------------------------------------------------------------------
__global__ __launch_bounds__(256) void prep_weights(
    const float* __restrict__ W0, const float* __restrict__ Wg,
    bf16_t* __restrict__ w0t, bf16_t* __restrict__ wgt)
{
  int e = blockIdx.x * 256 + threadIdx.x;
  if (e < kW0T) {
    int g  = e >> 15;
    int r  = e & 32767;
    int f  = r >> 9;             // 0..63 = ktl*8 + nt
    int ln = (r >> 3) & 63;
    int j  = r & 7;
    int ktl = f >> 3, nt = f & 7;
    int col = sigma16(nt * 16 + (ln & 15));
    int k   = ktl * 32 + ((ln >> 4) << 3) + j;
    w0t[e] = (bf16_t)W0[k * kH + g * 128 + col];
  } else if (e < kW0T + kWgT) {
    int e2 = e - kW0T;
    int g  = e2 / (12 * 16384);
    int r2 = e2 - g * (12 * 16384);
    int m  = r2 >> 14;           // l*4 + d
    int r  = r2 & 16383;
    int f  = r >> 9;             // 0..31 = ktl*8 + nt
    int ln = (r >> 3) & 63;
    int j  = r & 7;
    int ktl = f >> 3, nt = f & 7;
    int col = sigma16(nt * 16 + (ln & 15));
    int k   = ktl * 32 + ((ln >> 4) << 3) + j;
    int l   = m >> 2, d = m & 3;
    wgt[e2] = (bf16_t)Wg[((((l * kG + g) * kD + d) * 128) + k) * 128 + col];
  }
}

// ---------------------------------------------------------------------------
// Fused network, register-resident h, 16x16x32 MFMA variant for occupancy.
// Block = 64 rows x one group; 4 waves, wave w owns rows r0+16w..+15
// (lane row = base + (ln&15)), full n=0..127 (8 n-tiles, acc[8] f32x4).
// Arch regs/wave ~ acc 32 + keep/x0/res 48 + temps -> fits 128 => with the
// 39.4 KB LDS (single 32KB weight buffer + bias) gives 4 blocks/CU (16 waves).
// Per-step schedule: MFMA -> (lgkmcnt0+barrier: reads done) -> stage(m+1) ->
// epilogue overlaps staging flight -> (vmcnt0+barrier: weights landed).
// Final store via XOR-swizzled 64x128 f32 LDS transpose (fits the 32KB buf).
// ---------------------------------------------------------------------------
__global__ __launch_bounds__(256, 4) void resnext_fused(
    const float* __restrict__ x, const float* __restrict__ b0,
    const float* __restrict__ bg, const bf16_t* __restrict__ w0t,
    const bf16_t* __restrict__ wgt, float* __restrict__ out)
{
  __shared__ bf16_t sW[16384];        // 32 KB: weight buffer / f32 store tile
  __shared__ float  sBias[13 * 128];  // slot 0 = b0, slots 1..12 = bg steps

  const int tid = threadIdx.x;
  const int ln  = tid & 63;
  const int wv  = tid >> 6;
  const int l15 = ln & 15;
  const int c4  = ln >> 4;

  // bijective chunked XCD swizzle; logical order r-major with g fastest so the
  // 4 same-row blocks co-reside on one XCD (x fetched ~once).
  const int bid     = blockIdx.x;
  const int logical = (bid & 7) * 512 + (bid >> 3);
  const int g  = logical & 3;
  const int r0 = (logical >> 2) << 6;

  const bf16_t* wgt_g = wgt + g * (12 * 16384);

  // stage biases (b0 slice + 12 bg slices), logical-u order
  for (int i = tid; i < 13 * 128; i += 256) {
    float v;
    if (i < 128) v = b0[g * 128 + i];
    else {
      int m = (i - 128) >> 7, u = (i - 128) & 127;
      int l = m >> 2, d = m & 3;
      v = bg[((l * kG + g) * kD + d) * 128 + u];
    }
    sBias[i] = v;
  }

  // async stage of chain step m -> sW (8 frags/wave, 1KB each, lane*16B dest)
  auto stage = [&](int m) {
    #pragma unroll
    for (int i = 0; i < 8; ++i) {
      int frag = wv * 8 + i;
      __builtin_amdgcn_global_load_lds(
          (const __attribute__((address_space(1))) void*)(wgt_g + m * 16384 + frag * 512 + ln * 8),
          (__attribute__((address_space(3))) void*)(&sW[frag * 512]),
          16, 0, 0);
    }
  };

  stage(0);   // step-0 weights in flight under the initial GEMM

  f32x4 acc[8];
  #pragma unroll
  for (int nt = 0; nt < 8; ++nt)
    #pragma unroll
    for (int q = 0; q < 4; ++q) acc[nt][q] = 0.f;

  // ---------- initial GEMM: K=256, A (W0t) from global/L2, B from x
  {
    const bf16_t* w0g = w0t + g * 32768;
    const float* xb = x + (size_t)(r0 + wv * 16 + l15) * 256 + c4 * 8;
    #pragma unroll
    for (int ktl = 0; ktl < 8; ++ktl) {
      f32x4 xa = *(const f32x4*)(xb + ktl * 32);
      f32x4 xc = *(const f32x4*)(xb + ktl * 32 + 4);
      bf16x8 bfr;
      #pragma unroll
      for (int q = 0; q < 4; ++q) {
        bfr[q]     = (bf16_t)xa[q];
        bfr[q + 4] = (bf16_t)xc[q];
      }
      #pragma unroll
      for (int nt = 0; nt < 8; ++nt) {
        bf16x8 a = *(const bf16x8*)(w0g + (ktl * 8 + nt) * 512 + ln * 8);
        acc[nt] = MFMA16(a, bfr, acc[nt]);
      }
    }
  }
  __syncthreads();   // full drain ONCE: sBias + step-0 weights + x loads done

  bf16x8 keep[4], x0v[4], resv[4];

  // ---------- initial epilogue: relu(x@W0 + b0) -> keep/x0/resid registers
  #pragma unroll
  for (int nt = 0; nt < 8; ++nt) {
    const int ub = 4 * (nt & 1) + 8 * c4 + 32 * (nt >> 1);
    f32x4 bv = *(const f32x4*)(sBias + ub);
    #pragma unroll
    for (int q = 0; q < 4; ++q) {
      float v = fmaxf(acc[nt][q] + bv[q], 0.f);
      keep[nt >> 1][4 * (nt & 1) + q] = (bf16_t)v;
    }
  }
  #pragma unroll
  for (int t = 0; t < 4; ++t) { x0v[t] = keep[t]; resv[t] = keep[t]; }

  // ---------- chain steps m = 0..11, single weight buffer, 2 barriers/step
  #pragma unroll 1
  for (int m = 0; m < 12; ++m) {
    #pragma unroll
    for (int nt = 0; nt < 8; ++nt)
      #pragma unroll
      for (int q = 0; q < 4; ++q) acc[nt][q] = 0.f;

    #pragma unroll
    for (int ktl = 0; ktl < 4; ++ktl) {
      bf16x8 bfr = keep[ktl];
      #pragma unroll
      for (int nt = 0; nt < 8; ++nt) {
        bf16x8 a = *(const bf16x8*)(sW + (ktl * 8 + nt) * 512 + ln * 8);
        acc[nt] = MFMA16(a, bfr, acc[nt]);
      }
    }

    // all waves done reading sW -> safe to overwrite with step m+1
    asm volatile("s_waitcnt lgkmcnt(0)\n\ts_barrier" ::: "memory");
    if (m < 11) stage(m + 1);

    const bool layer_end = ((m & 3) == 3);
    const float* bptr = sBias + (m + 1) * 128;

    if (m < 11) {
      // epilogue overlaps the staging flight
      #pragma unroll
      for (int nt = 0; nt < 8; ++nt) {
        const int ub = 4 * (nt & 1) + 8 * c4 + 32 * (nt >> 1);
        f32x4 bv = *(const f32x4*)(bptr + ub);
        #pragma unroll
        for (int q = 0; q < 4; ++q) {
          float v = fmaxf(acc[nt][q] + bv[q], 0.f);
          if (layer_end)
            v = fmaxf(v + (float)resv[nt >> 1][4 * (nt & 1) + q], 0.f);
          keep[nt >> 1][4 * (nt & 1) + q] = (bf16_t)v;
        }
      }
      if (layer_end) {
        #pragma unroll
        for (int t = 0; t < 4; ++t) resv[t] = keep[t];
      }
      // step m+1 weights landed for every wave
      asm volatile("s_waitcnt vmcnt(0)\n\ts_barrier" ::: "memory");
    } else {
      // final: bias+relu, +resid relu, +x0 relu -> f32, via LDS transpose
      float fin[8][4];
      #pragma unroll
      for (int nt = 0; nt < 8; ++nt) {
        const int ub = 4 * (nt & 1) + 8 * c4 + 32 * (nt >> 1);
        f32x4 bv = *(const f32x4*)(bptr + ub);
        #pragma unroll
        for (int q = 0; q < 4; ++q) {
          float v = fmaxf(acc[nt][q] + bv[q], 0.f);
          v = fmaxf(v + (float)resv[nt >> 1][4 * (nt & 1) + q], 0.f);
          v = fmaxf(v + (float)x0v[nt >> 1][4 * (nt & 1) + q], 0.f);
          fin[nt][q] = v;
        }
      }

      // 64 x 128 f32 tile (32 KB) aliases sW; reads were barriered above
      float* sT = (float*)sW;
      const int row = wv * 16 + l15;
      #pragma unroll
      for (int nt = 0; nt < 8; ++nt) {
        const int ub = 4 * (nt & 1) + 8 * c4 + 32 * (nt >> 1);
        int col_s = ub ^ ((l15 & 7) << 2);
        f32x4 v;
        #pragma unroll
        for (int q = 0; q < 4; ++q) v[q] = fin[nt][q];
        *(f32x4*)(sT + row * 128 + col_s) = v;
      }
      __syncthreads();

      #pragma unroll
      for (int it = 0; it < 8; ++it) {
        int chunk = it * 256 + tid;
        int rw = chunk >> 5, c = chunk & 31;
        int col_s = (4 * c) ^ ((rw & 7) << 2);
        f32x4 v = *(const f32x4*)(sT + rw * 128 + col_s);
        *(f32x4*)(out + (size_t)(r0 + rw) * kH + g * 128 + 4 * c) = v;
      }
    }
  }
}

extern "C" void kernel_launch(void* const* d_in, const int* in_sizes, int n_in,
                              void* d_out, int out_size, void* d_ws, size_t ws_size,
                              hipStream_t stream) {
  const float* x  = (const float*)d_in[0];
  const float* W0 = (const float*)d_in[1];
  const float* b0 = (const float*)d_in[2];
  const float* Wg = (const float*)d_in[3];
  const float* bg = (const float*)d_in[4];
  float* outp = (float*)d_out;

  bf16_t* w0t = (bf16_t*)d_ws;
  bf16_t* wgt = w0t + kW0T;

  const int prep_total = kW0T + kWgT;
  prep_weights<<<(prep_total + 255) / 256, 256, 0, stream>>>(W0, Wg, w0t, wgt);

  resnext_fused<<<4096, 256, 0, stream>>>(x, b0, bg, w0t, wgt, outp);
}